// Round 1
// baseline (886.849 us; speedup 1.0000x reference)
//
#include <hip/hip_runtime.h>

// BioRNN: T=1000, B=4096, H=50, IN=8, OUT=6, fp32 throughout.
//   r   = relu(h)
//   y_t = r @ W_out^T + b_out          (r from PRE-update h)
//   h  += DT * (-h + x @ W_in^T + r @ W_rec^T + bias)
//
// Strategy: grid=512 blocks x 256 thr. Each block owns 8 batch elements.
// lane = (b = tid&7, jg = tid>>3). 56 "rows" (50 hidden + 6 output
// projections -- same inner product structure) are spread over the 32 jg
// groups: 14 rows per wave (6 jg with 2 rows, 2 jg with 1) -> every wave has
// identical instruction stream. Row weights live in VGPRs (loop-invariant).
// r is exchanged via a double-buffered LDS tile [2][8][52] (52-float stride
// = 208B -> 16B-aligned ds_read_b128, conflict-free). ONE barrier per step.
// x_t prefetched one step ahead into registers.

#define T_STEPS 1000
#define BATCH   4096
#define INSZ    8
#define H       50
#define OUTSZ   6
#define DT      0.1f
#define BPB     8          // batch elements per block
#define KP      52         // padded K stride (13 * float4; k=50,51 zero pad)

__global__ __launch_bounds__(256, 2)
void biornn_kernel(const float* __restrict__ xg,   // (T, B, INSZ)
                   const float* __restrict__ Wi,   // (H, INSZ)
                   const float* __restrict__ Wr,   // (H, H)
                   const float* __restrict__ bs,   // (H)
                   const float* __restrict__ Wo,   // (OUTSZ, H)
                   const float* __restrict__ bo,   // (OUTSZ)
                   float* __restrict__ out)        // (T, B, OUTSZ)
{
    __shared__ __align__(16) float r_lds[2][BPB][KP];

    const int tid = threadIdx.x;
    const int b   = tid & (BPB - 1);      // batch slot in block
    const int jg  = tid >> 3;             // 0..31 row-group
    const int w   = jg >> 3;              // wave 0..3
    const int q   = jg & 7;               // slot within wave
    const int base = w * 14;              // wave w owns rows [14w, 14w+14)
    const int  r0   = base + (q < 6 ? 2 * q : 6 + q);   // q=6->+12, q=7->+13
    const bool v1   = (q < 6);
    const int  r1   = v1 ? (r0 + 1) : 0;  // dummy 0 when invalid (weights=0)

    const bool h0row = (r0 < H);
    const bool h1row = v1 && (r1 < H);
    const bool y0row = (r0 >= H);
    const bool y1row = v1 && (r1 >= H);

    // ---- loop-invariant weights into registers ----
    float w0[KP], w1[KP], wi0[INSZ], wi1[INSZ];
    float b0 = 0.f, b1 = 0.f;
#pragma unroll
    for (int k = 0; k < KP; ++k) { w0[k] = 0.f; w1[k] = 0.f; }
#pragma unroll
    for (int i = 0; i < INSZ; ++i) { wi0[i] = 0.f; wi1[i] = 0.f; }

    if (h0row) {
#pragma unroll
        for (int k = 0; k < H; ++k) w0[k] = Wr[r0 * H + k];
#pragma unroll
        for (int i = 0; i < INSZ; ++i) wi0[i] = Wi[r0 * INSZ + i];
        b0 = bs[r0];
    } else {
        const int o = r0 - H;
#pragma unroll
        for (int k = 0; k < H; ++k) w0[k] = Wo[o * H + k];
        b0 = bo[o];
    }
    if (h1row) {
#pragma unroll
        for (int k = 0; k < H; ++k) w1[k] = Wr[r1 * H + k];
#pragma unroll
        for (int i = 0; i < INSZ; ++i) wi1[i] = Wi[r1 * INSZ + i];
        b1 = bs[r1];
    } else if (y1row) {
        const int o = r1 - H;
#pragma unroll
        for (int k = 0; k < H; ++k) w1[k] = Wo[o * H + k];
        b1 = bo[o];
    }

    // zero the k=50,51 pads of both buffers (read by ds_read_b128, weight=0)
    if (tid < 2 * BPB) {
        r_lds[tid >> 3][tid & (BPB - 1)][H]     = 0.f;
        r_lds[tid >> 3][tid & (BPB - 1)][H + 1] = 0.f;
    }

    // ---- per-lane state ----
    const int b_glob = blockIdx.x * BPB + b;
    float h0 = 0.f, h1 = 0.f;

    // x prefetch registers: hold x[t] for the current step
    const float* xp = xg + (size_t)b_glob * INSZ;
    float xv[INSZ];
#pragma unroll
    for (int i = 0; i < INSZ; i += 4) {
        float4 t4 = *(const float4*)(xp + i);
        xv[i] = t4.x; xv[i + 1] = t4.y; xv[i + 2] = t4.z; xv[i + 3] = t4.w;
    }
    xp += (size_t)BATCH * INSZ;

    // output offsets for y-rows (dummy 0 otherwise, never stored)
    int yo0 = y0row ? (b_glob * OUTSZ + (r0 - H)) : 0;
    int yo1 = y1row ? (b_glob * OUTSZ + (r1 - H)) : 0;

    for (int t = 0; t < T_STEPS; ++t) {
        const int cur = t & 1;

        // publish r = relu(h) for owned hidden rows into current buffer.
        // Double buffering: stragglers still read buf[cur^1] -> no WAR.
        const float rr0 = fmaxf(h0, 0.f);
        const float rr1 = fmaxf(h1, 0.f);
        if (h0row) r_lds[cur][b][r0] = rr0;
        if (h1row) r_lds[cur][b][r1] = rr1;
        __syncthreads();   // the ONLY barrier per step

        float acc0 = b0, acc1 = b1;
#pragma unroll
        for (int kc = 0; kc < KP / 4; ++kc) {
            const float4 rv = *(const float4*)&r_lds[cur][b][kc * 4];
            acc0 = fmaf(rv.x, w0[4 * kc + 0], acc0);
            acc1 = fmaf(rv.x, w1[4 * kc + 0], acc1);
            acc0 = fmaf(rv.y, w0[4 * kc + 1], acc0);
            acc1 = fmaf(rv.y, w1[4 * kc + 1], acc1);
            acc0 = fmaf(rv.z, w0[4 * kc + 2], acc0);
            acc1 = fmaf(rv.z, w1[4 * kc + 2], acc1);
            acc0 = fmaf(rv.w, w0[4 * kc + 3], acc0);
            acc1 = fmaf(rv.w, w1[4 * kc + 3], acc1);
        }
#pragma unroll
        for (int i = 0; i < INSZ; ++i) {
            acc0 = fmaf(xv[i], wi0[i], acc0);
            acc1 = fmaf(xv[i], wi1[i], acc1);
        }

        // prefetch x[t+1] (consumed next iteration; vmcnt wait lands there)
        if (t + 1 < T_STEPS) {
#pragma unroll
            for (int i = 0; i < INSZ; i += 4) {
                float4 t4 = *(const float4*)(xp + i);
                xv[i] = t4.x; xv[i + 1] = t4.y; xv[i + 2] = t4.z; xv[i + 3] = t4.w;
            }
            xp += (size_t)BATCH * INSZ;
        }

        // h <- h + DT*(acc - h). Harmless garbage on y-rows (h unused there).
        h0 += DT * (acc0 - h0);
        h1 += DT * (acc1 - h1);

        // y-rows: store y_t = acc (bias b_out already folded into init)
        if (y0row) out[(size_t)t * (BATCH * OUTSZ) + yo0] = acc0;
        if (y1row) out[(size_t)t * (BATCH * OUTSZ) + yo1] = acc1;
    }
}

extern "C" void kernel_launch(void* const* d_in, const int* in_sizes, int n_in,
                              void* d_out, int out_size, void* d_ws, size_t ws_size,
                              hipStream_t stream)
{
    const float* xg = (const float*)d_in[0];  // input_seq (1000,4096,8)
    const float* Wi = (const float*)d_in[1];  // W_in (50,8)
    const float* Wr = (const float*)d_in[2];  // W_rec (50,50)
    const float* bs = (const float*)d_in[3];  // bias (50)
    const float* Wo = (const float*)d_in[4];  // W_out_w (6,50)
    const float* bo = (const float*)d_in[5];  // W_out_b (6)
    float* outp = (float*)d_out;              // (1000,4096,6)

    dim3 grid(BATCH / BPB);   // 512 blocks
    dim3 block(256);          // 4 waves
    hipLaunchKernelGGL(biornn_kernel, grid, block, 0, stream,
                       xg, Wi, Wr, bs, Wo, bo, outp);
}